// Round 13
// baseline (182.059 us; speedup 1.0000x reference)
//
#include <hip/hip_runtime.h>
#include <hip/hip_bf16.h>
#include <math.h>

#define NN 4096
#define DD 127
#define HH 128
#define OUTD 3
#define NTYPES 6
#define SIM_THRESH 0.9f
#define BN_EPS 1e-5f
#define NREP 8    // accumulator replicas
#define KCH 128   // agg GEMM k-chunk

typedef unsigned short ushortT;
typedef __attribute__((ext_vector_type(8))) short short8;   // 8 bf16 (4 VGPRs)
typedef __attribute__((ext_vector_type(4))) float f32x4;

// round-to-nearest-even fp32 -> bf16 (bit pattern)
static __device__ inline ushortT f2bf(float f) {
    unsigned u = __float_as_uint(f);
    unsigned r = (u + 0x7fffu + ((u >> 16) & 1u)) >> 16;
    return (ushortT)r;
}
static __device__ inline float bf2f(ushortT b) {
    return __uint_as_float(((unsigned)b) << 16);
}

// ---------------------------------------------------------------------------
// Kernel P v6: blocks 0..7 convert W to bf16 (row-major). Blocks 8..263:
// 16-row strips -> xbf (row-major), x0T (transposed, for the agg GEMM's
// B-operand), fn, histogram, S0 type-sums (NREP replicas).
// ---------------------------------------------------------------------------
__global__ __launch_bounds__(256) void prep(
    const float* __restrict__ x_now, const int* __restrict__ sat,
    const float* __restrict__ Wl, const float* __restrict__ Wr,
    ushortT* __restrict__ Wbf, ushortT* __restrict__ xbf,
    ushortT* __restrict__ x0T, float4* __restrict__ fn,
    int* __restrict__ cnt, float* __restrict__ S0rep)
{
    int t = threadIdx.x;
    if (blockIdx.x < 8) {
        int baseidx = blockIdx.x * 8192;
        #pragma unroll
        for (int it = 0; it < 32; ++it) {
            int idx = baseidx + it * 256 + t;
            float v = (idx < 32768) ? Wl[idx] : Wr[idx - 32768];
            Wbf[idx] = f2bf(v);
        }
        return;
    }

    int sb = blockIdx.x - 8;           // strip 0..255
    int base = sb * 16;
    int rep = sb & (NREP - 1);
    __shared__ int stypes[16];
    int myti = -1;
    if (t < 16) {
        int row = base + t;
        int ti = sat[row]; ti = min(max(ti, 0), NTYPES - 1);
        stypes[t] = ti; myti = ti;
        const float* rp = x_now + (size_t)row * DD;
        float f0 = rp[0], f2 = rp[1], f3 = rp[2];
        float nrm = fmaxf(sqrtf(2.f * f0 * f0 + f2 * f2 + f3 * f3), 1e-12f);
        float inv = 1.f / nrm;
        fn[row] = make_float4(f0 * inv, f0 * inv, f2 * inv, f3 * inv);
    }
    #pragma unroll
    for (int it = 0; it < 8; ++it) {
        int lin = it * 256 + t;        // 0..2047
        int rl = lin >> 7, col = lin & 127;
        int row = base + rl;
        const float* rp = x_now + (size_t)row * DD;
        float v = (col == 0) ? rp[0] : rp[col - 1];
        xbf[(size_t)row * HH + col] = f2bf(v);
    }
    __syncthreads();
    // transposed copy (reads just-written xbf, L1-hot)
    #pragma unroll
    for (int it = 0; it < 8; ++it) {
        int lin = it * 256 + t;
        int c = lin >> 4, r = lin & 15;
        x0T[(size_t)c * NN + base + r] = xbf[(size_t)(base + r) * HH + c];
    }
    if (t < 64) {
        #pragma unroll
        for (int tt = 0; tt < NTYPES; ++tt) {
            unsigned long long m = __ballot(myti == tt);
            if (t == 0) {
                int c = __popcll(m);
                if (c) atomicAdd(&cnt[rep * NTYPES + tt], c);
            }
        }
    }
    if (t < 128) {
        float acc[NTYPES] = {0.f, 0.f, 0.f, 0.f, 0.f, 0.f};
        for (int r = 0; r < 16; ++r) {
            float v = bf2f(xbf[(size_t)(base + r) * HH + t]);
            int tt = stypes[r];
            #pragma unroll
            for (int q = 0; q < NTYPES; ++q) acc[q] += (tt == q) ? v : 0.f;
        }
        #pragma unroll
        for (int q = 0; q < NTYPES; ++q)
            atomicAdd(&S0rep[(rep * NTYPES + q) * HH + t], acc[q]);
    }
}

// ---------------------------------------------------------------------------
// Kernel A: build DENSE adjacency A (bf16 0/1, 4096x4096 = 32 MB) + deg.
// 4 rows/block, 1024 blocks. Coalesced 1KB writes per row-chunk. The dense
// form turns the scattered gather (the ~70cyc/instr TA wall, R8-R12) into
// a contiguous-streaming MFMA GEMM.
// ---------------------------------------------------------------------------
__global__ __launch_bounds__(256) void build_A(
    const float4* __restrict__ fn, const int* __restrict__ sat,
    const int* __restrict__ cnt, ushortT* __restrict__ Adense,
    float* __restrict__ deg)
{
    int i0 = blockIdx.x * 4;
    int t = threadIdx.x;
    float4 fi[4];
    int ti[4];
    #pragma unroll
    for (int r = 0; r < 4; ++r) {
        fi[r] = fn[i0 + r];
        int tt = sat[i0 + r];
        ti[r] = min(max(tt, 0), NTYPES - 1);
    }
    int cnts[4] = {0, 0, 0, 0};
    #pragma unroll
    for (int ch = 0; ch < 8; ++ch) {
        int j0 = ch * 512 + t * 2;
        float4 fa = fn[j0];
        float4 fb = fn[j0 + 1];
        int ta = sat[j0], tb = sat[j0 + 1];
        #pragma unroll
        for (int r = 0; r < 4; ++r) {
            float da = fi[r].x * fa.x + fi[r].y * fa.y
                     + fi[r].z * fa.z + fi[r].w * fa.w;
            float db = fi[r].x * fb.x + fi[r].y * fb.y
                     + fi[r].z * fb.z + fi[r].w * fb.w;
            bool pa = (ta != ti[r]) && (da > SIM_THRESH);
            bool pb = (tb != ti[r]) && (db > SIM_THRESH);
            unsigned val = (pa ? 0x3F80u : 0u) | (pb ? 0x3F800000u : 0u);
            *(unsigned*)&Adense[(size_t)(i0 + r) * NN + j0] = val;
            cnts[r] += (int)pa + (int)pb;
        }
    }
    int lane = t & 63, wv = t >> 6;
    for (int s = 32; s; s >>= 1) {
        #pragma unroll
        for (int r = 0; r < 4; ++r) cnts[r] += __shfl_down(cnts[r], s);
    }
    __shared__ int wcnt[4][4];
    if (lane == 0) {
        #pragma unroll
        for (int r = 0; r < 4; ++r) wcnt[wv][r] = cnts[r];
    }
    __syncthreads();
    if (t < 4) {
        int r = t;
        int total = wcnt[0][r] + wcnt[1][r] + wcnt[2][r] + wcnt[3][r];
        int ctot = 0;
        #pragma unroll
        for (int rr = 0; rr < NREP; ++rr) ctot += cnt[rr * NTYPES + ti[r]];
        deg[i0 + r] = fmaxf((float)(ctot - 1 + total), 1.0f);
    }
}

// ---------------------------------------------------------------------------
// Kernel AGG: e = A @ h via bf16 MFMA; m = (Ssum[type]-h+e)/deg -> mbf.
// Block: 16 rows x all 128 cols, K=4096 in 32 chunks of 128. A-chunk (4KB)
// and hT-chunk (32KB) staged to LDS with contiguous 16B loads; MFMA frags
// read from LDS (16B aligned, +8-ushort row pad -> 2-way max).
// A-frag A[m=lane&15][k=quad*8+j]; B-frag hT[n=lane&15][k=quad*8+j];
// D col=lane&15, row=quad*4+reg (m89-verified via R11 wgemm).
// ---------------------------------------------------------------------------
__global__ __launch_bounds__(256) void agg_kernel(
    const ushortT* __restrict__ Adense, const ushortT* __restrict__ hT,
    const ushortT* __restrict__ hrow, const float* __restrict__ Srep,
    const float* __restrict__ deg, const int* __restrict__ sat,
    ushortT* __restrict__ mbf)
{
    int t = threadIdx.x;
    int wv = t >> 6, lane = t & 63;
    int i0 = blockIdx.x * 16;

    __shared__ ushortT Abuf[16][KCH + 8];     // 4.25 KB
    __shared__ ushortT Hbuf[128][KCH + 8];    // 34 KB
    __shared__ float esh[16][HH];             // 8 KB
    __shared__ float Ssum[NTYPES][HH];        // 3 KB
    __shared__ float rdeg[16];
    __shared__ int ty[16];

    for (int e = t; e < NTYPES * HH; e += 256) {
        int q = e >> 7, c = e & 127;
        float s = 0.f;
        #pragma unroll
        for (int rr = 0; rr < NREP; ++rr)
            s += Srep[(rr * NTYPES + q) * HH + c];
        Ssum[q][c] = s;
    }
    if (t < 16) {
        rdeg[t] = 1.f / deg[i0 + t];
        int tt = sat[i0 + t];
        ty[t] = min(max(tt, 0), NTYPES - 1);
    }

    int p = lane & 15, q = lane >> 4;
    int ct0 = wv * 2, ct1 = wv * 2 + 1;
    f32x4 acc0 = {0.f, 0.f, 0.f, 0.f};
    f32x4 acc1 = {0.f, 0.f, 0.f, 0.f};

    for (int k0 = 0; k0 < NN; k0 += KCH) {
        {   // stage A chunk: 16 rows x 128 k (4 KB)
            int r = t >> 4, off = (t & 15) * 8;
            *(uint4*)&Abuf[r][off] =
                *(const uint4*)&Adense[(size_t)(i0 + r) * NN + k0 + off];
        }
        #pragma unroll
        for (int rd = 0; rd < 8; ++rd) {   // stage hT chunk: 128 x 128 (32 KB)
            int lin = rd * 256 + t;
            int row = lin >> 4, off = (lin & 15) * 8;
            *(uint4*)&Hbuf[row][off] =
                *(const uint4*)&hT[(size_t)row * NN + k0 + off];
        }
        __syncthreads();
        #pragma unroll
        for (int kk = 0; kk < KCH / 32; ++kk) {
            short8 a  = *(const short8*)&Abuf[p][kk * 32 + q * 8];
            short8 b0 = *(const short8*)&Hbuf[ct0 * 16 + p][kk * 32 + q * 8];
            short8 b1 = *(const short8*)&Hbuf[ct1 * 16 + p][kk * 32 + q * 8];
            acc0 = __builtin_amdgcn_mfma_f32_16x16x32_bf16(a, b0, acc0, 0, 0, 0);
            acc1 = __builtin_amdgcn_mfma_f32_16x16x32_bf16(a, b1, acc1, 0, 0, 0);
        }
        __syncthreads();
    }
    #pragma unroll
    for (int rg = 0; rg < 4; ++rg) {
        esh[q * 4 + rg][ct0 * 16 + p] = acc0[rg];
        esh[q * 4 + rg][ct1 * 16 + p] = acc1[rg];
    }
    __syncthreads();

    // epilogue: thread t -> row r = t>>4, cols c0..c0+7
    {
        int r = t >> 4, c0 = (t & 15) * 8;
        int i = i0 + r;
        float rd = rdeg[r];
        int tt = ty[r];
        uint4 hu = *(const uint4*)&hrow[(size_t)i * HH + c0];
        ushortT hv[8];
        hv[0] = (ushortT)(hu.x & 0xffff); hv[1] = (ushortT)(hu.x >> 16);
        hv[2] = (ushortT)(hu.y & 0xffff); hv[3] = (ushortT)(hu.y >> 16);
        hv[4] = (ushortT)(hu.z & 0xffff); hv[5] = (ushortT)(hu.z >> 16);
        hv[6] = (ushortT)(hu.w & 0xffff); hv[7] = (ushortT)(hu.w >> 16);
        ushortT res[8];
        #pragma unroll
        for (int e = 0; e < 8; ++e) {
            float m = (Ssum[tt][c0 + e] - bf2f(hv[e]) + esh[r][c0 + e]) * rd;
            res[e] = f2bf(m);
        }
        uint4 w;
        w.x = (unsigned)res[0] | ((unsigned)res[1] << 16);
        w.y = (unsigned)res[2] | ((unsigned)res[3] << 16);
        w.z = (unsigned)res[4] | ((unsigned)res[5] << 16);
        w.w = (unsigned)res[6] | ((unsigned)res[7] << 16);
        *(uint4*)&mbf[(size_t)i * HH + c0] = w;
    }
}

// ---------------------------------------------------------------------------
// Kernel M (weights GEMM): h_next = relu([mbf | hbf] @ [Wl | Wr]^T + bl).
// MODE 1: writes h1 bf16 row-major + h1T (for next agg) + next-layer S sums.
// MODE 2: writes h2 fp32 + BN stats.
// ---------------------------------------------------------------------------
template <int MODE>
__global__ __launch_bounds__(256) void gemm_kernel(
    const ushortT* __restrict__ mbf, const ushortT* __restrict__ hbf,
    const ushortT* __restrict__ Wlbf, const ushortT* __restrict__ Wrbf,
    const float* __restrict__ bl, const int* __restrict__ sat,
    float* __restrict__ hout, ushortT* __restrict__ houtbf,
    ushortT* __restrict__ houtT,
    float* __restrict__ acc0, float* __restrict__ acc1)
{
    int t = threadIdx.x;
    int wv = t >> 6, lane = t & 63;
    int p = lane & 15, q = lane >> 4;
    int i0 = blockIdx.x * 16;

    __shared__ float sh[16][129];
    __shared__ int stypes[16];
    if (t < 16) {
        int tt = sat[i0 + t];
        stypes[t] = min(max(tt, 0), NTYPES - 1);
    }

    const ushortT* arow_m = mbf + (size_t)(i0 + p) * HH + q * 8;
    const ushortT* arow_h = hbf + (size_t)(i0 + p) * HH + q * 8;
    short8 am[4], ah[4];
    #pragma unroll
    for (int s = 0; s < 4; ++s) {
        am[s] = *(const short8*)(arow_m + s * 32);
        ah[s] = *(const short8*)(arow_h + s * 32);
    }

    #pragma unroll
    for (int nt = 0; nt < 2; ++nt) {
        int n0 = (wv * 2 + nt) * 16;
        const ushortT* brow_l = Wlbf + (size_t)(n0 + p) * HH + q * 8;
        const ushortT* brow_r = Wrbf + (size_t)(n0 + p) * HH + q * 8;
        f32x4 acc = {0.f, 0.f, 0.f, 0.f};
        #pragma unroll
        for (int s = 0; s < 4; ++s) {
            short8 b = *(const short8*)(brow_l + s * 32);
            acc = __builtin_amdgcn_mfma_f32_16x16x32_bf16(am[s], b, acc, 0, 0, 0);
        }
        #pragma unroll
        for (int s = 0; s < 4; ++s) {
            short8 b = *(const short8*)(brow_r + s * 32);
            acc = __builtin_amdgcn_mfma_f32_16x16x32_bf16(ah[s], b, acc, 0, 0, 0);
        }
        int o = n0 + p;
        float bv = bl[o];
        #pragma unroll
        for (int rg = 0; rg < 4; ++rg) {
            float v = fmaxf(acc[rg] + bv, 0.f);
            sh[q * 4 + rg][o] = v;
        }
    }
    __syncthreads();

    #pragma unroll
    for (int e = 0; e < 8; ++e) {
        int lin = e * 256 + t;
        int rr = lin >> 7, cc = lin & 127;
        float v = sh[rr][cc];
        if (MODE == 1) houtbf[(size_t)i0 * HH + lin] = f2bf(v);
        else          hout[(size_t)i0 * HH + lin] = v;
    }
    if (MODE == 1) {
        #pragma unroll
        for (int e = 0; e < 8; ++e) {
            int lin = e * 256 + t;
            int c = lin >> 4, r = lin & 15;
            houtT[(size_t)c * NN + i0 + r] = f2bf(sh[r][c]);
        }
    }
    int rep = blockIdx.x & (NREP - 1);
    if (t < HH) {
        if (MODE == 1) {
            float accq[NTYPES] = {0.f, 0.f, 0.f, 0.f, 0.f, 0.f};
            for (int r = 0; r < 16; ++r) {
                float v = sh[r][t];
                int tt = stypes[r];
                #pragma unroll
                for (int qq = 0; qq < NTYPES; ++qq)
                    accq[qq] += (tt == qq) ? v : 0.f;
            }
            #pragma unroll
            for (int qq = 0; qq < NTYPES; ++qq)
                atomicAdd(&acc0[(rep * NTYPES + qq) * HH + t], accq[qq]);
        } else {
            float s = 0.f, s2 = 0.f;
            for (int r = 0; r < 16; ++r) {
                float v = sh[r][t];
                s += v; s2 += v * v;
            }
            atomicAdd(&acc0[rep * HH + t], s);
            atomicAdd(&acc1[rep * HH + t], s2);
        }
    }
}

// ---------------------------------------------------------------------------
// Kernel F: BN apply + head, one wave per row; sums the NREP stat replicas.
// ---------------------------------------------------------------------------
__global__ __launch_bounds__(256) void finalize(
    const float* __restrict__ h, const float* __restrict__ musum8,
    const float* __restrict__ varsum8, const float* __restrict__ gamma,
    const float* __restrict__ beta, const float* __restrict__ Wo,
    const float* __restrict__ bo, float* __restrict__ out_h,
    float* __restrict__ out_o)
{
    int t = threadIdx.x;
    int wv = t >> 6;
    int lane = t & 63;
    int i = blockIdx.x * 4 + wv;

    float2 mus = {0.f, 0.f}, vas = {0.f, 0.f};
    #pragma unroll
    for (int r = 0; r < NREP; ++r) {
        float2 a = ((const float2*)(musum8 + r * HH))[lane];
        float2 b = ((const float2*)(varsum8 + r * HH))[lane];
        mus.x += a.x; mus.y += a.y;
        vas.x += b.x; vas.y += b.y;
    }
    float2 ga  = ((const float2*)gamma)[lane];
    float2 be  = ((const float2*)beta)[lane];
    float mu0 = mus.x * (1.f / NN), mu1 = mus.y * (1.f / NN);
    float v0 = vas.x * (1.f / NN) - mu0 * mu0;
    float v1 = vas.y * (1.f / NN) - mu1 * mu1;
    float sc0 = ga.x / sqrtf(v0 + BN_EPS), sc1 = ga.y / sqrtf(v1 + BN_EPS);
    float sh0 = be.x - mu0 * sc0, sh1 = be.y - mu1 * sc1;

    float2 hv = ((const float2*)(h + (size_t)i * HH))[lane];
    float2 hb;
    hb.x = hv.x * sc0 + sh0;
    hb.y = hv.y * sc1 + sh1;
    ((float2*)(out_h + (size_t)i * HH))[lane] = hb;

    float2 w0 = ((const float2*)Wo)[lane];
    float2 w1 = ((const float2*)(Wo + HH))[lane];
    float2 w2 = ((const float2*)(Wo + 2 * HH))[lane];
    float p0 = hb.x * w0.x + hb.y * w0.y;
    float p1 = hb.x * w1.x + hb.y * w1.y;
    float p2 = hb.x * w2.x + hb.y * w2.y;
    for (int s = 32; s; s >>= 1) {
        p0 += __shfl_down(p0, s);
        p1 += __shfl_down(p1, s);
        p2 += __shfl_down(p2, s);
    }
    if (lane == 0) {
        out_o[(size_t)i * OUTD + 0] = p0 + bo[0];
        out_o[(size_t)i * OUTD + 1] = p1 + bo[1];
        out_o[(size_t)i * OUTD + 2] = p2 + bo[2];
    }
}

// ---------------------------------------------------------------------------
extern "C" void kernel_launch(void* const* d_in, const int* in_sizes, int n_in,
                              void* d_out, int out_size, void* d_ws, size_t ws_size,
                              hipStream_t stream)
{
    (void)in_sizes; (void)n_in; (void)out_size; (void)ws_size;
    const float* x_now = (const float*)d_in[0];
    const int*   sat   = (const int*)d_in[1];
    const float* Wl    = (const float*)d_in[2];
    const float* bl    = (const float*)d_in[3];
    const float* Wr    = (const float*)d_in[4];
    const float* gamma = (const float*)d_in[5];
    const float* beta  = (const float*)d_in[6];
    const float* Wo    = (const float*)d_in[7];
    const float* bo    = (const float*)d_in[8];

    float* ws = (float*)d_ws;
    float*  h2     = ws;                              // NN*HH f
    float4* fn     = (float4*)(h2 + (size_t)NN * HH); // NN float4
    float*  deg    = (float*)(fn + NN);               // NN
    // ---- zeroed accumulator region (one contiguous memset) ----
    int*    cnt    = (int*)(deg + NN);                // 64
    float*  S0rep  = (float*)(cnt + 64);              // 6144
    float*  S1rep  = S0rep + NREP * NTYPES * HH;      // 6144
    float*  mu8    = S1rep + NREP * NTYPES * HH;      // 1024
    float*  var8   = mu8 + NREP * HH;                 // 1024
    // ---- bf16 region ----
    ushortT* Wbf   = (ushortT*)(var8 + NREP * HH);    // 65536 us
    ushortT* x0bf  = Wbf + 65536;                     // NN*HH us
    ushortT* h1bf  = x0bf + (size_t)NN * HH;          // NN*HH us
    ushortT* mbf   = h1bf + (size_t)NN * HH;          // NN*HH us
    ushortT* x0T   = mbf + (size_t)NN * HH;           // NN*HH us
    ushortT* h1T   = x0T + (size_t)NN * HH;           // NN*HH us
    ushortT* Adense = h1T + (size_t)NN * HH;          // NN*NN us = 32 MB

    size_t zero_bytes = (64 + 2 * NREP * NTYPES * HH + 2 * NREP * HH)
                        * sizeof(float);
    hipMemsetAsync(cnt, 0, zero_bytes, stream);

    prep<<<264, 256, 0, stream>>>(x_now, sat, Wl, Wr, Wbf, x0bf, x0T, fn, cnt,
                                  S0rep);
    build_A<<<NN / 4, 256, 0, stream>>>(fn, sat, cnt, Adense, deg);

    // layer 1
    agg_kernel<<<NN / 16, 256, 0, stream>>>(Adense, x0T, x0bf, S0rep, deg, sat,
                                            mbf);
    gemm_kernel<1><<<NN / 16, 256, 0, stream>>>(
        mbf, x0bf, Wbf, Wbf + 32768, bl, sat, nullptr, h1bf, h1T,
        S1rep, nullptr);

    // layer 2
    agg_kernel<<<NN / 16, 256, 0, stream>>>(Adense, h1T, h1bf, S1rep, deg, sat,
                                            mbf);
    gemm_kernel<2><<<NN / 16, 256, 0, stream>>>(
        mbf, h1bf, Wbf + 16384, Wbf + 49152, bl + HH, sat, h2, nullptr, nullptr,
        mu8, var8);

    finalize<<<NN / 4, 256, 0, stream>>>(h2, mu8, var8, gamma, beta, Wo, bo,
                                         (float*)d_out, (float*)d_out + (size_t)NN * HH);
}

// Round 14
// 136.929 us; speedup vs baseline: 1.3296x; 1.3296x over previous
//
#include <hip/hip_runtime.h>
#include <hip/hip_bf16.h>
#include <math.h>

#define NN 4096
#define DD 127
#define HH 128
#define OUTD 3
#define NTYPES 6
#define SIM_THRESH 0.9f
#define BN_EPS 1e-5f
#define MROW 4    // rows per block in build_mask
#define NREP 8    // accumulator replicas
// Half-row neighbor list capacity. Half-degree ~ Binomial(1706, 0.05):
// mean 85, sigma 9 -> 256 = 19-sigma bound.
#define LMAXH 256

typedef unsigned short ushortT;
typedef __attribute__((ext_vector_type(8))) short short8;   // 8 bf16 (4 VGPRs)
typedef __attribute__((ext_vector_type(4))) float f32x4;

// round-to-nearest-even fp32 -> bf16 (bit pattern)
static __device__ inline ushortT f2bf(float f) {
    unsigned u = __float_as_uint(f);
    unsigned r = (u + 0x7fffu + ((u >> 16) & 1u)) >> 16;
    return (ushortT)r;
}

// ---------------------------------------------------------------------------
// Kernel P v4 (R11): blocks 0..7 convert W to bf16 (row-major — MFMA B
// fragment reads k-contiguous). Blocks 8..263: 16-row strips: x fp32 + bf16
// replica, fn, histogram, S0 type-sums (NREP replicas).
// ---------------------------------------------------------------------------
__global__ __launch_bounds__(256) void prep(
    const float* __restrict__ x_now, const int* __restrict__ sat,
    const float* __restrict__ Wl, const float* __restrict__ Wr,
    ushortT* __restrict__ Wbf, float* __restrict__ x,
    ushortT* __restrict__ xbf, float4* __restrict__ fn,
    int* __restrict__ cnt, float* __restrict__ S0rep)
{
    int t = threadIdx.x;
    if (blockIdx.x < 8) {
        int baseidx = blockIdx.x * 8192;
        #pragma unroll
        for (int it = 0; it < 32; ++it) {
            int idx = baseidx + it * 256 + t;
            float v = (idx < 32768) ? Wl[idx] : Wr[idx - 32768];
            Wbf[idx] = f2bf(v);
        }
        return;
    }

    int sb = blockIdx.x - 8;           // strip 0..255
    int base = sb * 16;
    int rep = sb & (NREP - 1);
    __shared__ int stypes[16];
    int myti = -1;
    if (t < 16) {
        int row = base + t;
        int ti = sat[row]; ti = min(max(ti, 0), NTYPES - 1);
        stypes[t] = ti; myti = ti;
        const float* rp = x_now + (size_t)row * DD;
        float f0 = rp[0], f2 = rp[1], f3 = rp[2];
        float nrm = fmaxf(sqrtf(2.f * f0 * f0 + f2 * f2 + f3 * f3), 1e-12f);
        float inv = 1.f / nrm;
        fn[row] = make_float4(f0 * inv, f0 * inv, f2 * inv, f3 * inv);
    }
    #pragma unroll
    for (int it = 0; it < 8; ++it) {
        int lin = it * 256 + t;        // 0..2047
        int rl = lin >> 7, col = lin & 127;
        int row = base + rl;
        const float* rp = x_now + (size_t)row * DD;
        float v = (col == 0) ? rp[0] : rp[col - 1];
        x[(size_t)row * HH + col] = v;
        xbf[(size_t)row * HH + col] = f2bf(v);
    }
    __syncthreads();
    if (t < 64) {
        #pragma unroll
        for (int tt = 0; tt < NTYPES; ++tt) {
            unsigned long long m = __ballot(myti == tt);
            if (t == 0) {
                int c = __popcll(m);
                if (c) atomicAdd(&cnt[rep * NTYPES + tt], c);
            }
        }
    }
    if (t < 128) {
        float acc[NTYPES] = {0.f, 0.f, 0.f, 0.f, 0.f, 0.f};
        for (int r = 0; r < 16; ++r) {
            float v = x[(size_t)(base + r) * HH + t];
            int tt = stypes[r];
            #pragma unroll
            for (int q = 0; q < NTYPES; ++q) acc[q] += (tt == q) ? v : 0.f;
        }
        #pragma unroll
        for (int q = 0; q < NTYPES; ++q)
            atomicAdd(&S0rep[(rep * NTYPES + q) * HH + t], acc[q]);
    }
}

// ---------------------------------------------------------------------------
// Kernel B v3 (R11): bitmask + degree; b-loop split across two thread-halves
// (serial depth 16). Bit layout: word w of row i, bit b <-> j = b*128 + w.
// ---------------------------------------------------------------------------
__global__ __launch_bounds__(256) void build_mask(
    const float4* __restrict__ fn, const int* __restrict__ sat,
    const int* __restrict__ cnt, unsigned* __restrict__ mask,
    float* __restrict__ deg)
{
    int i0 = blockIdx.x * MROW;
    int t = threadIdx.x;
    int w = t & 127;
    int half = t >> 7;
    float4 fi[MROW];
    int ti[MROW];
    #pragma unroll
    for (int r = 0; r < MROW; ++r) {
        fi[r] = fn[i0 + r];
        int tt = sat[i0 + r];
        ti[r] = min(max(tt, 0), NTYPES - 1);
    }
    unsigned word[MROW] = {0, 0, 0, 0};
    int bbase = half * 16;
    for (int bb = 0; bb < 16; ++bb) {
        int b = bbase + bb;
        int j = b * 128 + w;
        float4 fj = fn[j];
        int tj = sat[j];
        #pragma unroll
        for (int r = 0; r < MROW; ++r) {
            float dot = fi[r].x * fj.x + fi[r].y * fj.y
                      + fi[r].z * fj.z + fi[r].w * fj.w;
            if (tj != ti[r] && dot > SIM_THRESH) word[r] |= (1u << b);
        }
    }
    __shared__ unsigned wpart[MROW][128];
    if (half == 1) {
        #pragma unroll
        for (int r = 0; r < MROW; ++r) wpart[r][w] = word[r];
    }
    __syncthreads();
    __shared__ int wt[2][MROW];
    if (half == 0) {
        int pcs[MROW];
        #pragma unroll
        for (int r = 0; r < MROW; ++r) {
            unsigned full = word[r] | wpart[r][w];
            mask[(size_t)(i0 + r) * 128 + w] = full;
            pcs[r] = __popc(full);
        }
        int lane = w & 63, wv2 = w >> 6;
        for (int s = 32; s; s >>= 1) {
            #pragma unroll
            for (int r = 0; r < MROW; ++r) pcs[r] += __shfl_down(pcs[r], s);
        }
        if (lane == 0) {
            #pragma unroll
            for (int r = 0; r < MROW; ++r) wt[wv2][r] = pcs[r];
        }
    }
    __syncthreads();
    if (t < MROW) {
        int r = t;
        int ctot = 0;
        #pragma unroll
        for (int rr = 0; rr < NREP; ++rr) ctot += cnt[rr * NTYPES + ti[r]];
        float d = (float)(ctot - 1 + wt[0][r] + wt[1][r]);
        deg[i0 + r] = fmaxf(d, 1.0f);
    }
}

// ---------------------------------------------------------------------------
// Kernel G (R11 gather): two waves per row, bf16 gather; writes m as bf16.
// ---------------------------------------------------------------------------
__global__ __launch_bounds__(256, 8) void gather_kernel(
    const float* __restrict__ h, const ushortT* __restrict__ hbf,
    const unsigned* __restrict__ mask, const float* __restrict__ deg,
    const float* __restrict__ S, const int* __restrict__ sat,
    ushortT* __restrict__ mbf)
{
    int t = threadIdx.x;
    int wv = t >> 6;          // wave id 0..3
    int lane = t & 63;
    int r  = wv >> 1;         // row slot 0..1
    int hf = wv & 1;          // half 0..1
    int i0 = blockIdx.x * 2;
    int i = i0 + r;

    __shared__ ushortT list[4][LMAXH];                   // 2 KB
    __shared__ __align__(16) float hs[2][HH];            // 1 KB
    __shared__ __align__(16) float part[4][HH];          // 2 KB
    __shared__ int tarr[2];

    if (t < 2) {
        int tt = sat[i0 + t];
        tarr[t] = min(max(tt, 0), NTYPES - 1);
    }

    // ---- decode: wave (r,hf) owns mask words hf*64+lane of row i ----
    int widx = hf * 64 + lane;
    unsigned word = mask[(size_t)i * 128 + widx];
    int pc = __popc(word);
    int x = pc;
    for (int s = 1; s < 64; s <<= 1) {
        int v = __shfl_up(x, s);
        if (lane >= s) x += v;
    }
    int ncnt = __shfl(x, 63);
    int ofs = x - pc;
    unsigned ww = word;
    while (ww) {
        int b = __ffs(ww) - 1; ww &= ww - 1;
        list[wv][ofs++] = (ushortT)(b * 128 + widx);
    }
    if (hf == 0)
        ((float2*)hs[r])[lane] = ((const float2*)(h + (size_t)i * HH))[lane];

    // ---- gather own half-list from bf16 rows: 4 rows/instr, 6 deep ----
    int q = lane >> 4;        // 0..3 neighbor slot
    int c = lane & 15;        // 0..15 -> columns 8c..8c+7
    const uint4* __restrict__ hb4 = (const uint4*)hbf;
    float acc[8] = {0.f, 0.f, 0.f, 0.f, 0.f, 0.f, 0.f, 0.f};
#define BFACC(vv)                                                         \
    {                                                                     \
        acc[0] += __uint_as_float((vv).x << 16);                          \
        acc[1] += __uint_as_float((vv).x & 0xffff0000u);                  \
        acc[2] += __uint_as_float((vv).y << 16);                          \
        acc[3] += __uint_as_float((vv).y & 0xffff0000u);                  \
        acc[4] += __uint_as_float((vv).z << 16);                          \
        acc[5] += __uint_as_float((vv).z & 0xffff0000u);                  \
        acc[6] += __uint_as_float((vv).w << 16);                          \
        acc[7] += __uint_as_float((vv).w & 0xffff0000u);                  \
    }
    int g = 0;
    for (; g + 24 <= ncnt; g += 24) {
        int j0 = list[wv][g + q];
        int j1 = list[wv][g + 4 + q];
        int j2 = list[wv][g + 8 + q];
        int j3 = list[wv][g + 12 + q];
        int j4 = list[wv][g + 16 + q];
        int j5 = list[wv][g + 20 + q];
        uint4 v0 = hb4[j0 * 16 + c];
        uint4 v1 = hb4[j1 * 16 + c];
        uint4 v2 = hb4[j2 * 16 + c];
        uint4 v3 = hb4[j3 * 16 + c];
        uint4 v4 = hb4[j4 * 16 + c];
        uint4 v5 = hb4[j5 * 16 + c];
        BFACC(v0); BFACC(v1); BFACC(v2); BFACC(v3); BFACC(v4); BFACC(v5);
    }
    for (; g + 4 <= ncnt; g += 4) {
        int j0 = list[wv][g + q];
        uint4 v0 = hb4[j0 * 16 + c];
        BFACC(v0);
    }
    if (q < ncnt - g) {
        int j0 = list[wv][g + q];
        uint4 v0 = hb4[j0 * 16 + c];
        BFACC(v0);
    }
#undef BFACC
    #pragma unroll
    for (int d = 0; d < 8; ++d) {
        acc[d] += __shfl_down(acc[d], 32);
        acc[d] += __shfl_down(acc[d], 16);
    }
    if (lane < 16) {
        float4 p0 = {acc[0], acc[1], acc[2], acc[3]};
        float4 p1 = {acc[4], acc[5], acc[6], acc[7]};
        ((float4*)part[wv])[c * 2] = p0;
        ((float4*)part[wv])[c * 2 + 1] = p1;
    }
    __syncthreads();   // partials + tarr ready

    if (hf == 0 && lane < 32) {
        int cc = lane;
        float4 p0 = ((const float4*)part[wv])[cc];
        float4 p1 = ((const float4*)part[wv + 1])[cc];
        int ti = tarr[r];
        float rdeg = 1.f / deg[i];
        float4 hv = ((const float4*)hs[r])[cc];
        float4 Sv = {0.f, 0.f, 0.f, 0.f};
        #pragma unroll
        for (int rr = 0; rr < NREP; ++rr) {
            float4 sv = ((const float4*)S)[(rr * NTYPES + ti) * 32 + cc];
            Sv.x += sv.x; Sv.y += sv.y; Sv.z += sv.z; Sv.w += sv.w;
        }
        float4 m;
        m.x = (Sv.x - hv.x + p0.x + p1.x) * rdeg;
        m.y = (Sv.y - hv.y + p0.y + p1.y) * rdeg;
        m.z = (Sv.z - hv.z + p0.z + p1.z) * rdeg;
        m.w = (Sv.w - hv.w + p0.w + p1.w) * rdeg;
        ushort4 mb;
        mb.x = f2bf(m.x); mb.y = f2bf(m.y);
        mb.z = f2bf(m.z); mb.w = f2bf(m.w);
        ((ushort4*)(mbf + (size_t)i * HH))[cc] = mb;
    }
}

// ---------------------------------------------------------------------------
// Kernel M (MFMA GEMM, R11): hout = relu([mbf | hbf] @ [Wl | Wr]^T + bl).
// 256 blocks x 16 rows, K=256, bf16 16x16x32 MFMA; W read row-major as the
// B fragment. D layout col=lane&15, row=quad*4+reg (m89-verified).
// MODE 1: writes h1 fp32 + bf16 replica + next-layer type sums.
// MODE 2: writes h2 fp32 + BN stats.
// ---------------------------------------------------------------------------
template <int MODE>
__global__ __launch_bounds__(256) void gemm_kernel(
    const ushortT* __restrict__ mbf, const ushortT* __restrict__ hbf,
    const ushortT* __restrict__ Wlbf, const ushortT* __restrict__ Wrbf,
    const float* __restrict__ bl, const int* __restrict__ sat,
    float* __restrict__ hout, ushortT* __restrict__ houtbf,
    float* __restrict__ acc0, float* __restrict__ acc1)
{
    int t = threadIdx.x;
    int wv = t >> 6, lane = t & 63;
    int p = lane & 15, q = lane >> 4;
    int i0 = blockIdx.x * 16;

    __shared__ float sh[16][129];
    __shared__ int stypes[16];
    if (t < 16) {
        int tt = sat[i0 + t];
        stypes[t] = min(max(tt, 0), NTYPES - 1);
    }

    const ushortT* arow_m = mbf + (size_t)(i0 + p) * HH + q * 8;
    const ushortT* arow_h = hbf + (size_t)(i0 + p) * HH + q * 8;
    short8 am[4], ah[4];
    #pragma unroll
    for (int s = 0; s < 4; ++s) {
        am[s] = *(const short8*)(arow_m + s * 32);
        ah[s] = *(const short8*)(arow_h + s * 32);
    }

    #pragma unroll
    for (int nt = 0; nt < 2; ++nt) {
        int n0 = (wv * 2 + nt) * 16;
        const ushortT* brow_l = Wlbf + (size_t)(n0 + p) * HH + q * 8;
        const ushortT* brow_r = Wrbf + (size_t)(n0 + p) * HH + q * 8;
        f32x4 acc = {0.f, 0.f, 0.f, 0.f};
        #pragma unroll
        for (int s = 0; s < 4; ++s) {
            short8 b = *(const short8*)(brow_l + s * 32);
            acc = __builtin_amdgcn_mfma_f32_16x16x32_bf16(am[s], b, acc, 0, 0, 0);
        }
        #pragma unroll
        for (int s = 0; s < 4; ++s) {
            short8 b = *(const short8*)(brow_r + s * 32);
            acc = __builtin_amdgcn_mfma_f32_16x16x32_bf16(ah[s], b, acc, 0, 0, 0);
        }
        int o = n0 + p;
        float bv = bl[o];
        #pragma unroll
        for (int rg = 0; rg < 4; ++rg) {
            float v = fmaxf(acc[rg] + bv, 0.f);
            sh[q * 4 + rg][o] = v;
        }
    }
    __syncthreads();

    #pragma unroll
    for (int e = 0; e < 8; ++e) {
        int lin = e * 256 + t;
        int rr = lin >> 7, cc = lin & 127;
        float v = sh[rr][cc];
        hout[(size_t)i0 * HH + lin] = v;
        if (MODE == 1) houtbf[(size_t)i0 * HH + lin] = f2bf(v);
    }
    int rep = blockIdx.x & (NREP - 1);
    if (t < HH) {
        if (MODE == 1) {
            float accq[NTYPES] = {0.f, 0.f, 0.f, 0.f, 0.f, 0.f};
            for (int r = 0; r < 16; ++r) {
                float v = sh[r][t];
                int tt = stypes[r];
                #pragma unroll
                for (int qq = 0; qq < NTYPES; ++qq)
                    accq[qq] += (tt == qq) ? v : 0.f;
            }
            #pragma unroll
            for (int qq = 0; qq < NTYPES; ++qq)
                atomicAdd(&acc0[(rep * NTYPES + qq) * HH + t], accq[qq]);
        } else {
            float s = 0.f, s2 = 0.f;
            for (int r = 0; r < 16; ++r) {
                float v = sh[r][t];
                s += v; s2 += v * v;
            }
            atomicAdd(&acc0[rep * HH + t], s);
            atomicAdd(&acc1[rep * HH + t], s2);
        }
    }
}

// ---------------------------------------------------------------------------
// Kernel F: BN apply + head, one wave per row; sums the NREP stat replicas.
// ---------------------------------------------------------------------------
__global__ __launch_bounds__(256) void finalize(
    const float* __restrict__ h, const float* __restrict__ musum8,
    const float* __restrict__ varsum8, const float* __restrict__ gamma,
    const float* __restrict__ beta, const float* __restrict__ Wo,
    const float* __restrict__ bo, float* __restrict__ out_h,
    float* __restrict__ out_o)
{
    int t = threadIdx.x;
    int wv = t >> 6;
    int lane = t & 63;
    int i = blockIdx.x * 4 + wv;

    float2 mus = {0.f, 0.f}, vas = {0.f, 0.f};
    #pragma unroll
    for (int r = 0; r < NREP; ++r) {
        float2 a = ((const float2*)(musum8 + r * HH))[lane];
        float2 b = ((const float2*)(varsum8 + r * HH))[lane];
        mus.x += a.x; mus.y += a.y;
        vas.x += b.x; vas.y += b.y;
    }
    float2 ga  = ((const float2*)gamma)[lane];
    float2 be  = ((const float2*)beta)[lane];
    float mu0 = mus.x * (1.f / NN), mu1 = mus.y * (1.f / NN);
    float v0 = vas.x * (1.f / NN) - mu0 * mu0;
    float v1 = vas.y * (1.f / NN) - mu1 * mu1;
    float sc0 = ga.x / sqrtf(v0 + BN_EPS), sc1 = ga.y / sqrtf(v1 + BN_EPS);
    float sh0 = be.x - mu0 * sc0, sh1 = be.y - mu1 * sc1;

    float2 hv = ((const float2*)(h + (size_t)i * HH))[lane];
    float2 hb;
    hb.x = hv.x * sc0 + sh0;
    hb.y = hv.y * sc1 + sh1;
    ((float2*)(out_h + (size_t)i * HH))[lane] = hb;

    float2 w0 = ((const float2*)Wo)[lane];
    float2 w1 = ((const float2*)(Wo + HH))[lane];
    float2 w2 = ((const float2*)(Wo + 2 * HH))[lane];
    float p0 = hb.x * w0.x + hb.y * w0.y;
    float p1 = hb.x * w1.x + hb.y * w1.y;
    float p2 = hb.x * w2.x + hb.y * w2.y;
    for (int s = 32; s; s >>= 1) {
        p0 += __shfl_down(p0, s);
        p1 += __shfl_down(p1, s);
        p2 += __shfl_down(p2, s);
    }
    if (lane == 0) {
        out_o[(size_t)i * OUTD + 0] = p0 + bo[0];
        out_o[(size_t)i * OUTD + 1] = p1 + bo[1];
        out_o[(size_t)i * OUTD + 2] = p2 + bo[2];
    }
}

// ---------------------------------------------------------------------------
extern "C" void kernel_launch(void* const* d_in, const int* in_sizes, int n_in,
                              void* d_out, int out_size, void* d_ws, size_t ws_size,
                              hipStream_t stream)
{
    (void)in_sizes; (void)n_in; (void)out_size; (void)ws_size;
    const float* x_now = (const float*)d_in[0];
    const int*   sat   = (const int*)d_in[1];
    const float* Wl    = (const float*)d_in[2];
    const float* bl    = (const float*)d_in[3];
    const float* Wr    = (const float*)d_in[4];
    const float* gamma = (const float*)d_in[5];
    const float* beta  = (const float*)d_in[6];
    const float* Wo    = (const float*)d_in[7];
    const float* bo    = (const float*)d_in[8];

    float* ws = (float*)d_ws;
    float* x0 = ws;                               // 524288 f
    float* h1 = x0 + (size_t)NN * HH;             // 524288 f
    float* h2 = h1 + (size_t)NN * HH;             // 524288 f
    ushortT* Wbf  = (ushortT*)(h2 + (size_t)NN * HH);   // 65536 us [Wl0,Wl1,Wr0,Wr1]
    ushortT* x0bf = Wbf + 65536;                  // 524288 us
    ushortT* h1bf = x0bf + (size_t)NN * HH;       // 524288 us
    ushortT* mbf  = h1bf + (size_t)NN * HH;       // 524288 us (shared by both layers)
    float4* fn = (float4*)(mbf + (size_t)NN * HH);      // 4096 float4
    unsigned* mask = (unsigned*)((float*)fn + 4 * NN);  // 524288 words
    float* deg = (float*)(mask + (size_t)NN * 128);     // 4096
    // ---- zeroed accumulator region (one contiguous memset) ----
    int*   cnt   = (int*)(deg + NN);              // NREP*6 (reserve 64)
    float* S0rep = (float*)(cnt + 64);            // 6144
    float* S1rep = S0rep + NREP * NTYPES * HH;    // 6144
    float* mu8   = S1rep + NREP * NTYPES * HH;    // 1024
    float* var8  = mu8 + NREP * HH;               // 1024

    size_t zero_bytes = (64 + 2 * NREP * NTYPES * HH + 2 * NREP * HH)
                        * sizeof(float);
    hipMemsetAsync(cnt, 0, zero_bytes, stream);

    prep<<<264, 256, 0, stream>>>(x_now, sat, Wl, Wr, Wbf, x0, x0bf, fn, cnt,
                                  S0rep);
    build_mask<<<NN / MROW, 256, 0, stream>>>(fn, sat, cnt, mask, deg);

    // layer 1
    gather_kernel<<<NN / 2, 256, 0, stream>>>(x0, x0bf, mask, deg, S0rep, sat,
                                              mbf);
    gemm_kernel<1><<<NN / 16, 256, 0, stream>>>(
        mbf, x0bf, Wbf, Wbf + 32768, bl, sat, h1, h1bf, S1rep, nullptr);

    // layer 2
    gather_kernel<<<NN / 2, 256, 0, stream>>>(h1, h1bf, mask, deg, S1rep, sat,
                                              mbf);
    gemm_kernel<2><<<NN / 16, 256, 0, stream>>>(
        mbf, h1bf, Wbf + 16384, Wbf + 49152, bl + HH, sat, h2, nullptr,
        mu8, var8);

    finalize<<<NN / 4, 256, 0, stream>>>(h2, mu8, var8, gamma, beta, Wo, bo,
                                         (float*)d_out, (float*)d_out + (size_t)NN * HH);
}

// Round 15
// 135.834 us; speedup vs baseline: 1.3403x; 1.0081x over previous
//
#include <hip/hip_runtime.h>
#include <hip/hip_bf16.h>
#include <math.h>

#define NN 4096
#define DD 127
#define HH 128
#define OUTD 3
#define NTYPES 6
#define SIM_THRESH 0.9f
#define BN_EPS 1e-5f
#define MROW 4    // rows per block in build_mask
#define NREP 8    // accumulator replicas
// Half-row neighbor list capacity. Half-degree ~ Binomial(1706, 0.05):
// mean 85, sigma 9 -> 256 = 19-sigma bound.
#define LMAXH 256

typedef unsigned short ushortT;
typedef unsigned char ucharT;
typedef __attribute__((ext_vector_type(8))) short short8;   // 8 bf16 (4 VGPRs)
typedef __attribute__((ext_vector_type(4))) float f32x4;
typedef __attribute__((ext_vector_type(2))) float f32x2;

// round-to-nearest-even fp32 -> bf16 (bit pattern)
static __device__ inline ushortT f2bf(float f) {
    unsigned u = __float_as_uint(f);
    unsigned r = (u + 0x7fffu + ((u >> 16) & 1u)) >> 16;
    return (ushortT)r;
}
// pack 2 floats -> 2 fp8 e4m3 bytes (HW RNE)
static __device__ inline ushortT pk_fp8(float a, float b) {
    int p = __builtin_amdgcn_cvt_pk_fp8_f32(a, b, 0, false);
    return (ushortT)(p & 0xffff);
}

// ---------------------------------------------------------------------------
// Kernel P v7: blocks 0..7 convert W to bf16 (row-major). Blocks 8..263:
// 16-row strips: x fp32 + bf16 replica + FP8 gather replica, fn, histogram,
// S0 type-sums (NREP replicas).
// ---------------------------------------------------------------------------
__global__ __launch_bounds__(256) void prep(
    const float* __restrict__ x_now, const int* __restrict__ sat,
    const float* __restrict__ Wl, const float* __restrict__ Wr,
    ushortT* __restrict__ Wbf, float* __restrict__ x,
    ushortT* __restrict__ xbf, ucharT* __restrict__ x8,
    float4* __restrict__ fn, int* __restrict__ cnt,
    float* __restrict__ S0rep)
{
    int t = threadIdx.x;
    if (blockIdx.x < 8) {
        int baseidx = blockIdx.x * 8192;
        #pragma unroll
        for (int it = 0; it < 32; ++it) {
            int idx = baseidx + it * 256 + t;
            float v = (idx < 32768) ? Wl[idx] : Wr[idx - 32768];
            Wbf[idx] = f2bf(v);
        }
        return;
    }

    int sb = blockIdx.x - 8;           // strip 0..255
    int base = sb * 16;
    int rep = sb & (NREP - 1);
    __shared__ int stypes[16];
    int myti = -1;
    if (t < 16) {
        int row = base + t;
        int ti = sat[row]; ti = min(max(ti, 0), NTYPES - 1);
        stypes[t] = ti; myti = ti;
        const float* rp = x_now + (size_t)row * DD;
        float f0 = rp[0], f2 = rp[1], f3 = rp[2];
        float nrm = fmaxf(sqrtf(2.f * f0 * f0 + f2 * f2 + f3 * f3), 1e-12f);
        float inv = 1.f / nrm;
        fn[row] = make_float4(f0 * inv, f0 * inv, f2 * inv, f3 * inv);
    }
    #pragma unroll
    for (int it = 0; it < 4; ++it) {
        int lin = it * 512 + t * 2;    // even element pairs, 0..2046
        int rl = lin >> 7, col = lin & 127;   // col even
        int row = base + rl;
        const float* rp = x_now + (size_t)row * DD;
        float v0 = (col == 0) ? rp[0] : rp[col - 1];
        float v1 = rp[col];            // x[:,col+1] = x_now[:,col]
        x[(size_t)row * HH + col] = v0;
        x[(size_t)row * HH + col + 1] = v1;
        xbf[(size_t)row * HH + col] = f2bf(v0);
        xbf[(size_t)row * HH + col + 1] = f2bf(v1);
        *(ushortT*)&x8[(size_t)row * HH + col] = pk_fp8(v0, v1);
    }
    __syncthreads();
    if (t < 64) {
        #pragma unroll
        for (int tt = 0; tt < NTYPES; ++tt) {
            unsigned long long m = __ballot(myti == tt);
            if (t == 0) {
                int c = __popcll(m);
                if (c) atomicAdd(&cnt[rep * NTYPES + tt], c);
            }
        }
    }
    if (t < 128) {
        float acc[NTYPES] = {0.f, 0.f, 0.f, 0.f, 0.f, 0.f};
        for (int r = 0; r < 16; ++r) {
            float v = x[(size_t)(base + r) * HH + t];
            int tt = stypes[r];
            #pragma unroll
            for (int q = 0; q < NTYPES; ++q) acc[q] += (tt == q) ? v : 0.f;
        }
        #pragma unroll
        for (int q = 0; q < NTYPES; ++q)
            atomicAdd(&S0rep[(rep * NTYPES + q) * HH + t], acc[q]);
    }
}

// ---------------------------------------------------------------------------
// Kernel B v3 (R11): bitmask + degree; b-loop split across two thread-halves.
// ---------------------------------------------------------------------------
__global__ __launch_bounds__(256) void build_mask(
    const float4* __restrict__ fn, const int* __restrict__ sat,
    const int* __restrict__ cnt, unsigned* __restrict__ mask,
    float* __restrict__ deg)
{
    int i0 = blockIdx.x * MROW;
    int t = threadIdx.x;
    int w = t & 127;
    int half = t >> 7;
    float4 fi[MROW];
    int ti[MROW];
    #pragma unroll
    for (int r = 0; r < MROW; ++r) {
        fi[r] = fn[i0 + r];
        int tt = sat[i0 + r];
        ti[r] = min(max(tt, 0), NTYPES - 1);
    }
    unsigned word[MROW] = {0, 0, 0, 0};
    int bbase = half * 16;
    for (int bb = 0; bb < 16; ++bb) {
        int b = bbase + bb;
        int j = b * 128 + w;
        float4 fj = fn[j];
        int tj = sat[j];
        #pragma unroll
        for (int r = 0; r < MROW; ++r) {
            float dot = fi[r].x * fj.x + fi[r].y * fj.y
                      + fi[r].z * fj.z + fi[r].w * fj.w;
            if (tj != ti[r] && dot > SIM_THRESH) word[r] |= (1u << b);
        }
    }
    __shared__ unsigned wpart[MROW][128];
    if (half == 1) {
        #pragma unroll
        for (int r = 0; r < MROW; ++r) wpart[r][w] = word[r];
    }
    __syncthreads();
    __shared__ int wt[2][MROW];
    if (half == 0) {
        int pcs[MROW];
        #pragma unroll
        for (int r = 0; r < MROW; ++r) {
            unsigned full = word[r] | wpart[r][w];
            mask[(size_t)(i0 + r) * 128 + w] = full;
            pcs[r] = __popc(full);
        }
        int lane = w & 63, wv2 = w >> 6;
        for (int s = 32; s; s >>= 1) {
            #pragma unroll
            for (int r = 0; r < MROW; ++r) pcs[r] += __shfl_down(pcs[r], s);
        }
        if (lane == 0) {
            #pragma unroll
            for (int r = 0; r < MROW; ++r) wt[wv2][r] = pcs[r];
        }
    }
    __syncthreads();
    if (t < MROW) {
        int r = t;
        int ctot = 0;
        #pragma unroll
        for (int rr = 0; rr < NREP; ++rr) ctot += cnt[rr * NTYPES + ti[r]];
        float d = (float)(ctot - 1 + wt[0][r] + wt[1][r]);
        deg[i0 + r] = fmaxf(d, 1.0f);
    }
}

// ---------------------------------------------------------------------------
// Kernel G v3: two waves per row; FP8 gather (rows 128 B -> 8 rows per
// wave-instruction, halving scattered VMEM instructions vs bf16). Decode
// from mask as R11. lane = (q,c): q=lane>>3 neighbor slot 0..7, c=lane&7
// -> 16-col chunk. HW cvt_pk_f32_fp8 unpack; fp32 accumulate; m -> bf16.
// ---------------------------------------------------------------------------
__global__ __launch_bounds__(256, 4) void gather_kernel(
    const float* __restrict__ h, const ucharT* __restrict__ h8,
    const unsigned* __restrict__ mask, const float* __restrict__ deg,
    const float* __restrict__ S, const int* __restrict__ sat,
    ushortT* __restrict__ mbf)
{
    int t = threadIdx.x;
    int wv = t >> 6;          // wave id 0..3
    int lane = t & 63;
    int r  = wv >> 1;         // row slot 0..1
    int hf = wv & 1;          // half 0..1
    int i0 = blockIdx.x * 2;
    int i = i0 + r;

    __shared__ ushortT list[4][LMAXH];                   // 2 KB
    __shared__ __align__(16) float hs[2][HH];            // 1 KB
    __shared__ __align__(16) float part[4][HH];          // 2 KB
    __shared__ int tarr[2];

    if (t < 2) {
        int tt = sat[i0 + t];
        tarr[t] = min(max(tt, 0), NTYPES - 1);
    }

    // ---- decode: wave (r,hf) owns mask words hf*64+lane of row i ----
    int widx = hf * 64 + lane;
    unsigned word = mask[(size_t)i * 128 + widx];
    int pc = __popc(word);
    int x = pc;
    for (int s = 1; s < 64; s <<= 1) {
        int v = __shfl_up(x, s);
        if (lane >= s) x += v;
    }
    int ncnt = __shfl(x, 63);
    int ofs = x - pc;
    unsigned ww = word;
    while (ww) {
        int b = __ffs(ww) - 1; ww &= ww - 1;
        list[wv][ofs++] = (ushortT)(b * 128 + widx);
    }
    if (hf == 0)
        ((float2*)hs[r])[lane] = ((const float2*)(h + (size_t)i * HH))[lane];

    // ---- fp8 gather: 8 rows/instr, 3 instr in flight (24 rows/iter) ----
    int q = lane >> 3;        // 0..7 neighbor slot
    int c = lane & 7;         // 0..7 -> columns 16c..16c+15
    const uint4* __restrict__ hb = (const uint4*)h8;   // row j at hb[j*8+c]
    float acc[16];
    #pragma unroll
    for (int d = 0; d < 16; ++d) acc[d] = 0.f;
#define F8ACC(u4)                                                          \
    {                                                                      \
        f32x2 r0 = __builtin_amdgcn_cvt_pk_f32_fp8((int)(u4).x, false);    \
        f32x2 r1 = __builtin_amdgcn_cvt_pk_f32_fp8((int)(u4).x, true);     \
        f32x2 r2 = __builtin_amdgcn_cvt_pk_f32_fp8((int)(u4).y, false);    \
        f32x2 r3 = __builtin_amdgcn_cvt_pk_f32_fp8((int)(u4).y, true);     \
        f32x2 r4 = __builtin_amdgcn_cvt_pk_f32_fp8((int)(u4).z, false);    \
        f32x2 r5 = __builtin_amdgcn_cvt_pk_f32_fp8((int)(u4).z, true);     \
        f32x2 r6 = __builtin_amdgcn_cvt_pk_f32_fp8((int)(u4).w, false);    \
        f32x2 r7 = __builtin_amdgcn_cvt_pk_f32_fp8((int)(u4).w, true);     \
        acc[0] += r0.x;  acc[1] += r0.y;  acc[2] += r1.x;  acc[3] += r1.y; \
        acc[4] += r2.x;  acc[5] += r2.y;  acc[6] += r3.x;  acc[7] += r3.y; \
        acc[8] += r4.x;  acc[9] += r4.y;  acc[10] += r5.x; acc[11] += r5.y;\
        acc[12] += r6.x; acc[13] += r6.y; acc[14] += r7.x; acc[15] += r7.y;\
    }
    int g = 0;
    for (; g + 24 <= ncnt; g += 24) {
        int j0 = list[wv][g + q];
        int j1 = list[wv][g + 8 + q];
        int j2 = list[wv][g + 16 + q];
        uint4 v0 = hb[j0 * 8 + c];
        uint4 v1 = hb[j1 * 8 + c];
        uint4 v2 = hb[j2 * 8 + c];
        F8ACC(v0); F8ACC(v1); F8ACC(v2);
    }
    for (; g + 8 <= ncnt; g += 8) {
        int j0 = list[wv][g + q];
        uint4 v0 = hb[j0 * 8 + c];
        F8ACC(v0);
    }
    if (q < ncnt - g) {
        int j0 = list[wv][g + q];
        uint4 v0 = hb[j0 * 8 + c];
        F8ACC(v0);
    }
#undef F8ACC
    // reduce across the 8 neighbor slots: lanes 0..7 end with column sums
    #pragma unroll
    for (int d = 0; d < 16; ++d) {
        acc[d] += __shfl_down(acc[d], 32);
        acc[d] += __shfl_down(acc[d], 16);
        acc[d] += __shfl_down(acc[d], 8);
    }
    if (lane < 8) {
        #pragma unroll
        for (int k = 0; k < 4; ++k) {
            float4 p = {acc[4 * k], acc[4 * k + 1],
                        acc[4 * k + 2], acc[4 * k + 3]};
            ((float4*)part[wv])[c * 4 + k] = p;
        }
    }
    __syncthreads();   // partials + tarr ready

    if (hf == 0 && lane < 32) {
        int cc = lane;
        float4 p0 = ((const float4*)part[wv])[cc];
        float4 p1 = ((const float4*)part[wv + 1])[cc];
        int ti = tarr[r];
        float rdeg = 1.f / deg[i];
        float4 hv = ((const float4*)hs[r])[cc];
        float4 Sv = {0.f, 0.f, 0.f, 0.f};
        #pragma unroll
        for (int rr = 0; rr < NREP; ++rr) {
            float4 sv = ((const float4*)S)[(rr * NTYPES + ti) * 32 + cc];
            Sv.x += sv.x; Sv.y += sv.y; Sv.z += sv.z; Sv.w += sv.w;
        }
        float4 m;
        m.x = (Sv.x - hv.x + p0.x + p1.x) * rdeg;
        m.y = (Sv.y - hv.y + p0.y + p1.y) * rdeg;
        m.z = (Sv.z - hv.z + p0.z + p1.z) * rdeg;
        m.w = (Sv.w - hv.w + p0.w + p1.w) * rdeg;
        ushort4 mb;
        mb.x = f2bf(m.x); mb.y = f2bf(m.y);
        mb.z = f2bf(m.z); mb.w = f2bf(m.w);
        ((ushort4*)(mbf + (size_t)i * HH))[cc] = mb;
    }
}

// ---------------------------------------------------------------------------
// Kernel M (MFMA GEMM, R11): hout = relu([mbf | hbf] @ [Wl | Wr]^T + bl).
// MODE 1: writes h1 fp32 + bf16 replica + FP8 replica + next-layer S sums.
// MODE 2: writes h2 fp32 + BN stats.
// ---------------------------------------------------------------------------
template <int MODE>
__global__ __launch_bounds__(256) void gemm_kernel(
    const ushortT* __restrict__ mbf, const ushortT* __restrict__ hbf,
    const ushortT* __restrict__ Wlbf, const ushortT* __restrict__ Wrbf,
    const float* __restrict__ bl, const int* __restrict__ sat,
    float* __restrict__ hout, ushortT* __restrict__ houtbf,
    ucharT* __restrict__ hout8,
    float* __restrict__ acc0, float* __restrict__ acc1)
{
    int t = threadIdx.x;
    int wv = t >> 6, lane = t & 63;
    int p = lane & 15, q = lane >> 4;
    int i0 = blockIdx.x * 16;

    __shared__ float sh[16][129];
    __shared__ int stypes[16];
    if (t < 16) {
        int tt = sat[i0 + t];
        stypes[t] = min(max(tt, 0), NTYPES - 1);
    }

    const ushortT* arow_m = mbf + (size_t)(i0 + p) * HH + q * 8;
    const ushortT* arow_h = hbf + (size_t)(i0 + p) * HH + q * 8;
    short8 am[4], ah[4];
    #pragma unroll
    for (int s = 0; s < 4; ++s) {
        am[s] = *(const short8*)(arow_m + s * 32);
        ah[s] = *(const short8*)(arow_h + s * 32);
    }

    #pragma unroll
    for (int nt = 0; nt < 2; ++nt) {
        int n0 = (wv * 2 + nt) * 16;
        const ushortT* brow_l = Wlbf + (size_t)(n0 + p) * HH + q * 8;
        const ushortT* brow_r = Wrbf + (size_t)(n0 + p) * HH + q * 8;
        f32x4 acc = {0.f, 0.f, 0.f, 0.f};
        #pragma unroll
        for (int s = 0; s < 4; ++s) {
            short8 b = *(const short8*)(brow_l + s * 32);
            acc = __builtin_amdgcn_mfma_f32_16x16x32_bf16(am[s], b, acc, 0, 0, 0);
        }
        #pragma unroll
        for (int s = 0; s < 4; ++s) {
            short8 b = *(const short8*)(brow_r + s * 32);
            acc = __builtin_amdgcn_mfma_f32_16x16x32_bf16(ah[s], b, acc, 0, 0, 0);
        }
        int o = n0 + p;
        float bv = bl[o];
        #pragma unroll
        for (int rg = 0; rg < 4; ++rg) {
            float v = fmaxf(acc[rg] + bv, 0.f);
            sh[q * 4 + rg][o] = v;
        }
    }
    __syncthreads();

    if (MODE == 1) {
        #pragma unroll
        for (int e = 0; e < 4; ++e) {
            int lin = e * 512 + t * 2;
            int rr = lin >> 7, cc = lin & 127;
            float v0 = sh[rr][cc], v1 = sh[rr][cc + 1];
            hout[(size_t)i0 * HH + lin] = v0;
            hout[(size_t)i0 * HH + lin + 1] = v1;
            houtbf[(size_t)i0 * HH + lin] = f2bf(v0);
            houtbf[(size_t)i0 * HH + lin + 1] = f2bf(v1);
            *(ushortT*)&hout8[(size_t)i0 * HH + lin] = pk_fp8(v0, v1);
        }
    } else {
        #pragma unroll
        for (int e = 0; e < 8; ++e) {
            int lin = e * 256 + t;
            int rr = lin >> 7, cc = lin & 127;
            hout[(size_t)i0 * HH + lin] = sh[rr][cc];
        }
    }
    int rep = blockIdx.x & (NREP - 1);
    if (t < HH) {
        if (MODE == 1) {
            float accq[NTYPES] = {0.f, 0.f, 0.f, 0.f, 0.f, 0.f};
            for (int r = 0; r < 16; ++r) {
                float v = sh[r][t];
                int tt = stypes[r];
                #pragma unroll
                for (int qq = 0; qq < NTYPES; ++qq)
                    accq[qq] += (tt == qq) ? v : 0.f;
            }
            #pragma unroll
            for (int qq = 0; qq < NTYPES; ++qq)
                atomicAdd(&acc0[(rep * NTYPES + qq) * HH + t], accq[qq]);
        } else {
            float s = 0.f, s2 = 0.f;
            for (int r = 0; r < 16; ++r) {
                float v = sh[r][t];
                s += v; s2 += v * v;
            }
            atomicAdd(&acc0[rep * HH + t], s);
            atomicAdd(&acc1[rep * HH + t], s2);
        }
    }
}

// ---------------------------------------------------------------------------
// Kernel F: BN apply + head, one wave per row; sums the NREP stat replicas.
// ---------------------------------------------------------------------------
__global__ __launch_bounds__(256) void finalize(
    const float* __restrict__ h, const float* __restrict__ musum8,
    const float* __restrict__ varsum8, const float* __restrict__ gamma,
    const float* __restrict__ beta, const float* __restrict__ Wo,
    const float* __restrict__ bo, float* __restrict__ out_h,
    float* __restrict__ out_o)
{
    int t = threadIdx.x;
    int wv = t >> 6;
    int lane = t & 63;
    int i = blockIdx.x * 4 + wv;

    float2 mus = {0.f, 0.f}, vas = {0.f, 0.f};
    #pragma unroll
    for (int r = 0; r < NREP; ++r) {
        float2 a = ((const float2*)(musum8 + r * HH))[lane];
        float2 b = ((const float2*)(varsum8 + r * HH))[lane];
        mus.x += a.x; mus.y += a.y;
        vas.x += b.x; vas.y += b.y;
    }
    float2 ga  = ((const float2*)gamma)[lane];
    float2 be  = ((const float2*)beta)[lane];
    float mu0 = mus.x * (1.f / NN), mu1 = mus.y * (1.f / NN);
    float v0 = vas.x * (1.f / NN) - mu0 * mu0;
    float v1 = vas.y * (1.f / NN) - mu1 * mu1;
    float sc0 = ga.x / sqrtf(v0 + BN_EPS), sc1 = ga.y / sqrtf(v1 + BN_EPS);
    float sh0 = be.x - mu0 * sc0, sh1 = be.y - mu1 * sc1;

    float2 hv = ((const float2*)(h + (size_t)i * HH))[lane];
    float2 hb;
    hb.x = hv.x * sc0 + sh0;
    hb.y = hv.y * sc1 + sh1;
    ((float2*)(out_h + (size_t)i * HH))[lane] = hb;

    float2 w0 = ((const float2*)Wo)[lane];
    float2 w1 = ((const float2*)(Wo + HH))[lane];
    float2 w2 = ((const float2*)(Wo + 2 * HH))[lane];
    float p0 = hb.x * w0.x + hb.y * w0.y;
    float p1 = hb.x * w1.x + hb.y * w1.y;
    float p2 = hb.x * w2.x + hb.y * w2.y;
    for (int s = 32; s; s >>= 1) {
        p0 += __shfl_down(p0, s);
        p1 += __shfl_down(p1, s);
        p2 += __shfl_down(p2, s);
    }
    if (lane == 0) {
        out_o[(size_t)i * OUTD + 0] = p0 + bo[0];
        out_o[(size_t)i * OUTD + 1] = p1 + bo[1];
        out_o[(size_t)i * OUTD + 2] = p2 + bo[2];
    }
}

// ---------------------------------------------------------------------------
extern "C" void kernel_launch(void* const* d_in, const int* in_sizes, int n_in,
                              void* d_out, int out_size, void* d_ws, size_t ws_size,
                              hipStream_t stream)
{
    (void)in_sizes; (void)n_in; (void)out_size; (void)ws_size;
    const float* x_now = (const float*)d_in[0];
    const int*   sat   = (const int*)d_in[1];
    const float* Wl    = (const float*)d_in[2];
    const float* bl    = (const float*)d_in[3];
    const float* Wr    = (const float*)d_in[4];
    const float* gamma = (const float*)d_in[5];
    const float* beta  = (const float*)d_in[6];
    const float* Wo    = (const float*)d_in[7];
    const float* bo    = (const float*)d_in[8];

    float* ws = (float*)d_ws;
    float* x0 = ws;                               // 524288 f
    float* h1 = x0 + (size_t)NN * HH;             // 524288 f
    float* h2 = h1 + (size_t)NN * HH;             // 524288 f
    ushortT* Wbf  = (ushortT*)(h2 + (size_t)NN * HH);   // 65536 us [Wl0,Wl1,Wr0,Wr1]
    ushortT* x0bf = Wbf + 65536;                  // 524288 us
    ushortT* h1bf = x0bf + (size_t)NN * HH;       // 524288 us
    ushortT* mbf  = h1bf + (size_t)NN * HH;       // 524288 us (shared by both layers)
    ucharT* x08   = (ucharT*)(mbf + (size_t)NN * HH);   // 524288 B fp8
    ucharT* h18   = x08 + (size_t)NN * HH;              // 524288 B fp8
    float4* fn = (float4*)(h18 + (size_t)NN * HH);      // 4096 float4
    unsigned* mask = (unsigned*)((float*)fn + 4 * NN);  // 524288 words
    float* deg = (float*)(mask + (size_t)NN * 128);     // 4096
    // ---- zeroed accumulator region (one contiguous memset) ----
    int*   cnt   = (int*)(deg + NN);              // NREP*6 (reserve 64)
    float* S0rep = (float*)(cnt + 64);            // 6144
    float* S1rep = S0rep + NREP * NTYPES * HH;    // 6144
    float* mu8   = S1rep + NREP * NTYPES * HH;    // 1024
    float* var8  = mu8 + NREP * HH;               // 1024

    size_t zero_bytes = (64 + 2 * NREP * NTYPES * HH + 2 * NREP * HH)
                        * sizeof(float);
    hipMemsetAsync(cnt, 0, zero_bytes, stream);

    prep<<<264, 256, 0, stream>>>(x_now, sat, Wl, Wr, Wbf, x0, x0bf, x08, fn,
                                  cnt, S0rep);
    build_mask<<<NN / MROW, 256, 0, stream>>>(fn, sat, cnt, mask, deg);

    // layer 1
    gather_kernel<<<NN / 2, 256, 0, stream>>>(x0, x08, mask, deg, S0rep, sat,
                                              mbf);
    gemm_kernel<1><<<NN / 16, 256, 0, stream>>>(
        mbf, x0bf, Wbf, Wbf + 32768, bl, sat, h1, h1bf, h18, S1rep, nullptr);

    // layer 2
    gather_kernel<<<NN / 2, 256, 0, stream>>>(h1, h18, mask, deg, S1rep, sat,
                                              mbf);
    gemm_kernel<2><<<NN / 16, 256, 0, stream>>>(
        mbf, h1bf, Wbf + 16384, Wbf + 49152, bl + HH, sat, h2, nullptr, nullptr,
        mu8, var8);

    finalize<<<NN / 4, 256, 0, stream>>>(h2, mu8, var8, gamma, beta, Wo, bo,
                                         (float*)d_out, (float*)d_out + (size_t)NN * HH);
}